// Round 7
// baseline (1197.556 us; speedup 1.0000x reference)
//
#include <hip/hip_runtime.h>
#include <hip/hip_bf16.h>

// GCN 2-layer, N=100000, E=1.6M, 64->64(relu)->32.
// out[d] = dis[d]*(sum_{s in N(d)} dis[s]*h[s] + dis[d]*h[d]) + b  (per layer).
// Edge-parallel pipeline (3 kernels + memset), NO pedge lists at all:
//  pass1+gemm1: partition edges into 782 dst-range buckets (128 dsts each,
//    rec = (src<<7)|(dst&127)) + global per-dst degree count (1.6M atomics,
//    overlapped with gemm blocks) + x@W1 -> h1u bf16 (single rounding).
//  agg1_gemm2_ep: one block per bucket. Reads its rec bucket SEQUENTIALLY,
//    gathers h1u rows edge-parallel (8 lanes x 16B), accumulates weighted
//    rows into LDS acc[128][68] via ds_add_f32 (stride 68: 16B-aligned +
//    bank-spread). Then self+bias+relu in place (z stays in LDS, f32) and
//    a 128x32 gemm tile @ W2 -> h2s bf16 (pre-scaled by dis, coalesced).
//  agg2_ep: same pattern on h2s (4 lanes x 16B, acc[128][36]), writes out.
// Degree model verified r3-r6: each XCD compulsorily pulls the full gather
// table (8 x table) at ~2.3 TB/s random-fetch ceiling; this round removes
// structure traffic (pedge round trip + pass2) instead of fighting that floor.

constexpr int N = 100000;
constexpr int E = 1600000;
constexpr int NBINS = 782;     // dst-ranges of 128
constexpr int CAP  = 2688;     // records per range (mean 2046, +14 sigma)
constexpr int P1B  = 391;      // pass1 blocks (4096 edges each)
constexpr int GB   = 1563;     // gemm1 blocks (64 rows each)

// ---- fused: pass1 partition + degree count (bid<P1B) | gemm1 (else) ----
__global__ void __launch_bounds__(256) fused_pass1_gemm1(
    const float* __restrict__ x, const float* __restrict__ W1,
    __hip_bfloat16* __restrict__ h1u,
    const int* __restrict__ src, const int* __restrict__ dst,
    int* __restrict__ cursor, int* __restrict__ cnt,
    unsigned* __restrict__ rec) {
    __shared__ float ws[64][64];    // 16 KB (pass1 reuses as int scratch)
    __shared__ float xsT[64][64];   // 16 KB
    const int bid = blockIdx.x;
    const int t = threadIdx.x;
    if (bid < P1B) {
        int* hist  = (int*)ws;          // 784
        int* rbase = hist + 784;        // 784
        int* rcur  = rbase + 784;       // 784
        for (int i = t; i < 784; i += 256) hist[i] = 0;
        __syncthreads();
        int myd[16], mys[16];
        const int e0 = bid * 4096;
#pragma unroll
        for (int it = 0; it < 16; ++it) {
            int idx = e0 + it * 256 + t;
            bool ok = idx < E;
            myd[it] = ok ? dst[idx] : -1;
            mys[it] = ok ? src[idx] : 0;
            if (ok) {
                atomicAdd(&hist[myd[it] >> 7], 1);
                atomicAdd(&cnt[myd[it]], 1);   // global degree (no-return)
            }
        }
        __syncthreads();
        for (int i = t; i < 784; i += 256) {
            int h = hist[i];
            rbase[i] = (h > 0) ? atomicAdd(&cursor[i], h) : 0;
            rcur[i] = 0;
        }
        __syncthreads();
#pragma unroll
        for (int it = 0; it < 16; ++it) {
            if (myd[it] >= 0) {
                int cb = myd[it] >> 7;
                int r = atomicAdd(&rcur[cb], 1);
                int pos = rbase[cb] + r;
                if (pos < CAP)
                    rec[(size_t)cb * CAP + pos] =
                        ((unsigned)mys[it] << 7) | ((unsigned)myd[it] & 127u);
            }
        }
    } else {
        // ---- gemm block: 64 rows, outer-product 4x4 per thread ----
        const int row0 = (bid - P1B) * 64;
        for (int i = t * 4; i < 64 * 64; i += 1024) {
            float4 v = *(const float4*)(W1 + i);
            ws[i >> 6][i & 63]       = v.x;
            ws[i >> 6][(i & 63) + 1] = v.y;
            ws[i >> 6][(i & 63) + 2] = v.z;
            ws[i >> 6][(i & 63) + 3] = v.w;
        }
        {
            const int r  = t & 63;
            const int k0 = (t >> 6) * 16;
            const int gr = row0 + r;
            if (gr < N) {
#pragma unroll
                for (int kk = 0; kk < 16; kk += 4) {
                    float4 v = *(const float4*)(x + (size_t)gr * 64 + k0 + kk);
                    xsT[k0 + kk][r]     = v.x;
                    xsT[k0 + kk + 1][r] = v.y;
                    xsT[k0 + kk + 2][r] = v.z;
                    xsT[k0 + kk + 3][r] = v.w;
                }
            } else {
#pragma unroll
                for (int kk = 0; kk < 16; ++kk) xsT[k0 + kk][r] = 0.0f;
            }
        }
        __syncthreads();
        const int c4 = (t & 15) * 4;
        const int r4 = (t >> 4) * 4;
        float acc[4][4];
#pragma unroll
        for (int i = 0; i < 4; ++i)
#pragma unroll
            for (int j = 0; j < 4; ++j) acc[i][j] = 0.0f;
#pragma unroll 4
        for (int k = 0; k < 64; ++k) {
            float4 wv = *(const float4*)&ws[k][c4];
            float4 xv = *(const float4*)&xsT[k][r4];
            float xa[4] = {xv.x, xv.y, xv.z, xv.w};
            float wa[4] = {wv.x, wv.y, wv.z, wv.w};
#pragma unroll
            for (int i = 0; i < 4; ++i)
#pragma unroll
                for (int j = 0; j < 4; ++j) acc[i][j] += xa[i] * wa[j];
        }
#pragma unroll
        for (int i = 0; i < 4; ++i) {
            const int gr = row0 + r4 + i;
            if (gr < N) {
                unsigned short o[4];
#pragma unroll
                for (int j = 0; j < 4; ++j)
                    o[j] = __bfloat16_as_ushort(__float2bfloat16(acc[i][j]));
                *(ushort4*)((unsigned short*)h1u + (size_t)gr * 64 + c4) =
                    *(const ushort4*)o;
            }
        }
    }
}

__device__ __forceinline__ void lds_add8_w(float* a, uint4 r, float w) {
    const unsigned u[4] = {r.x, r.y, r.z, r.w};
#pragma unroll
    for (int k = 0; k < 4; ++k) {
        atomicAdd(a + 2 * k,     __uint_as_float(u[k] << 16) * w);
        atomicAdd(a + 2 * k + 1, __uint_as_float(u[k] & 0xffff0000u) * w);
    }
}

__device__ __forceinline__ void lds_add8(float* a, uint4 r) {
    const unsigned u[4] = {r.x, r.y, r.z, r.w};
#pragma unroll
    for (int k = 0; k < 4; ++k) {
        atomicAdd(a + 2 * k,     __uint_as_float(u[k] << 16));
        atomicAdd(a + 2 * k + 1, __uint_as_float(u[k] & 0xffff0000u));
    }
}

// ---- edge-parallel layer-1 agg + gemm2: one block per 128-dst bucket ----
__global__ void __launch_bounds__(256) agg1_gemm2_ep(
    const __hip_bfloat16* __restrict__ h1u, const unsigned* __restrict__ rec,
    const int* __restrict__ cursor, const int* __restrict__ cnt,
    const float* __restrict__ b, const float* __restrict__ W2,
    __hip_bfloat16* __restrict__ h2s) {
    __shared__ float accL[128 * 68];   // 34.8 KB, stride 68: aligned + spread
    __shared__ float ws[64][32];       // W2
    __shared__ float dis_l[128];
    const int t = threadIdx.x;
    const int cb = blockIdx.x;
    for (int i = t; i < 128 * 68; i += 256) accL[i] = 0.0f;
    for (int i = t; i < 64 * 32; i += 256) ws[i >> 5][i & 31] = W2[i];
    if (t < 128) dis_l[t] = 0.0f;
    __syncthreads();

    int m = cursor[cb];
    if (m > CAP) m = CAP;
    const unsigned* rb_ = rec + (size_t)cb * CAP;
    const unsigned short* hp = (const unsigned short*)h1u;
    const int oct = t & 7;   // feature octet: 8 lanes x 16B per edge
    int i = t >> 3;          // 32 edges per block-iter, unroll 2
    for (; i + 32 < m; i += 64) {
        unsigned u0 = rb_[i], u1 = rb_[i + 32];
        unsigned s0 = u0 >> 7, s1 = u1 >> 7;
        float w0 = rsqrtf((float)cnt[s0] + 1.0f);
        float w1 = rsqrtf((float)cnt[s1] + 1.0f);
        uint4 r0 = *(const uint4*)(hp + (size_t)s0 * 64 + oct * 8);
        uint4 r1 = *(const uint4*)(hp + (size_t)s1 * 64 + oct * 8);
        lds_add8_w(&accL[(u0 & 127u) * 68 + oct * 8], r0, w0);
        lds_add8_w(&accL[(u1 & 127u) * 68 + oct * 8], r1, w1);
    }
    for (; i < m; i += 32) {
        unsigned u0 = rb_[i];
        unsigned s0 = u0 >> 7;
        float w0 = rsqrtf((float)cnt[s0] + 1.0f);
        uint4 r0 = *(const uint4*)(hp + (size_t)s0 * 64 + oct * 8);
        lds_add8_w(&accL[(u0 & 127u) * 68 + oct * 8], r0, w0);
    }
    __syncthreads();

    // self + bias + relu in place: z (f32) stays in accL
    const int row0 = cb * 128;
    {
        const int nl = t >> 1;
        const int half = t & 1;
        const int n = row0 + nl;
        if (n < N) {
            const float dn = rsqrtf((float)cnt[n] + 1.0f);
            if (half == 0) dis_l[nl] = dn;
            float* ap = &accL[nl * 68 + half * 32];
            const unsigned short* srp = hp + (size_t)n * 64 + half * 32;
            const float* bp = b + half * 32;
#pragma unroll
            for (int k = 0; k < 4; ++k) {
                uint4 v = *(const uint4*)(srp + k * 8);
                float4 bA = *(const float4*)(bp + k * 8);
                float4 bB = *(const float4*)(bp + k * 8 + 4);
                const unsigned uu[4] = {v.x, v.y, v.z, v.w};
                float bb[8] = {bA.x, bA.y, bA.z, bA.w, bB.x, bB.y, bB.z, bB.w};
#pragma unroll
                for (int q = 0; q < 4; ++q) {
                    float lo = __uint_as_float(uu[q] << 16);
                    float hi = __uint_as_float(uu[q] & 0xffff0000u);
                    int i0 = k * 8 + 2 * q;
                    ap[i0]     = fmaxf(dn * (ap[i0]     + dn * lo) + bb[2 * q],     0.0f);
                    ap[i0 + 1] = fmaxf(dn * (ap[i0 + 1] + dn * hi) + bb[2 * q + 1], 0.0f);
                }
            }
        }
    }
    __syncthreads();

    // gemm phase: 128x32 tile, thread = 1 col x 4 rows x 4 groups
    const int cc = t & 31;
    const int rbse = (t >> 5) * 4;
#pragma unroll
    for (int g = 0; g < 4; ++g) {
        const int r0_ = g * 32 + rbse;
        float oacc[4] = {0.f, 0.f, 0.f, 0.f};
        for (int k0 = 0; k0 < 64; k0 += 4) {
            float w0 = ws[k0][cc], w1 = ws[k0 + 1][cc];
            float w2 = ws[k0 + 2][cc], w3 = ws[k0 + 3][cc];
#pragma unroll
            for (int ii = 0; ii < 4; ++ii) {
                float4 xv = *(const float4*)&accL[(r0_ + ii) * 68 + k0];
                oacc[ii] += xv.x * w0 + xv.y * w1 + xv.z * w2 + xv.w * w3;
            }
        }
#pragma unroll
        for (int ii = 0; ii < 4; ++ii) {
            const int row = row0 + r0_ + ii;
            if (row < N)
                ((unsigned short*)h2s)[(size_t)row * 32 + cc] =
                    __bfloat16_as_ushort(
                        __float2bfloat16(oacc[ii] * dis_l[r0_ + ii]));
        }
    }
}

// ---- edge-parallel layer-2 agg: one block per bucket; h2s pre-scaled ----
__global__ void __launch_bounds__(256) agg2_ep(
    const __hip_bfloat16* __restrict__ h2s, const unsigned* __restrict__ rec,
    const int* __restrict__ cursor, const int* __restrict__ cnt,
    const float* __restrict__ b, float* __restrict__ out) {
    __shared__ float accL[128 * 36];   // 18.4 KB
    const int t = threadIdx.x;
    const int cb = blockIdx.x;
    for (int i = t; i < 128 * 36; i += 256) accL[i] = 0.0f;
    __syncthreads();

    int m = cursor[cb];
    if (m > CAP) m = CAP;
    const unsigned* rb_ = rec + (size_t)cb * CAP;
    const unsigned short* hp = (const unsigned short*)h2s;
    const int oct = t & 3;   // 4 lanes x 16B per edge
    int i = t >> 2;          // 64 edges per block-iter, unroll 2
    for (; i + 64 < m; i += 128) {
        unsigned u0 = rb_[i], u1 = rb_[i + 64];
        uint4 r0 = *(const uint4*)(hp + (size_t)(u0 >> 7) * 32 + oct * 8);
        uint4 r1 = *(const uint4*)(hp + (size_t)(u1 >> 7) * 32 + oct * 8);
        lds_add8(&accL[(u0 & 127u) * 36 + oct * 8], r0);
        lds_add8(&accL[(u1 & 127u) * 36 + oct * 8], r1);
    }
    for (; i < m; i += 64) {
        unsigned u0 = rb_[i];
        uint4 r0 = *(const uint4*)(hp + (size_t)(u0 >> 7) * 32 + oct * 8);
        lds_add8(&accL[(u0 & 127u) * 36 + oct * 8], r0);
    }
    __syncthreads();

    // self + bias + write out (f32), coalesced
    const int row0 = cb * 128;
    const int nl = t >> 1;
    const int half = t & 1;
    const int n = row0 + nl;
    if (n >= N) return;
    const float dn = rsqrtf((float)cnt[n] + 1.0f);
    const float* ap = &accL[nl * 36 + half * 16];
    const unsigned short* srp = hp + (size_t)n * 32 + half * 16;
    const float* bp = b + half * 16;
    float* op = out + (size_t)n * 32 + half * 16;
#pragma unroll
    for (int k = 0; k < 2; ++k) {
        uint4 v = *(const uint4*)(srp + k * 8);
        float4 bA = *(const float4*)(bp + k * 8);
        float4 bB = *(const float4*)(bp + k * 8 + 4);
        const unsigned uu[4] = {v.x, v.y, v.z, v.w};
        float o[8];
#pragma unroll
        for (int q = 0; q < 4; ++q) {
            float lo = __uint_as_float(uu[q] << 16);
            float hi = __uint_as_float(uu[q] & 0xffff0000u);
            o[2 * q]     = dn * (ap[k * 8 + 2 * q]     + lo);
            o[2 * q + 1] = dn * (ap[k * 8 + 2 * q + 1] + hi);
        }
        *(float4*)(op + k * 8)     = make_float4(o[0] + bA.x, o[1] + bA.y,
                                                 o[2] + bA.z, o[3] + bA.w);
        *(float4*)(op + k * 8 + 4) = make_float4(o[4] + bB.x, o[5] + bB.y,
                                                 o[6] + bB.z, o[7] + bB.w);
    }
}

extern "C" void kernel_launch(void* const* d_in, const int* in_sizes, int n_in,
                              void* d_out, int out_size, void* d_ws, size_t ws_size,
                              hipStream_t stream) {
    const float* x  = (const float*)d_in[0];
    const int*   ei = (const int*)d_in[1];
    const float* W1 = (const float*)d_in[2];
    const float* b1 = (const float*)d_in[3];
    const float* W2 = (const float*)d_in[4];
    const float* b2 = (const float*)d_in[5];
    float* out = (float*)d_out;

    const int* src = ei;
    const int* dst = ei + E;

    constexpr size_t NP = 100352;
    int*      cursor = (int*)d_ws;                             // 1024 ints
    int*      cnt    = cursor + 1024;                          // NP ints
    unsigned* rec    = (unsigned*)(cnt + NP);                  // NBINS*CAP u32
    __hip_bfloat16* h1u = (__hip_bfloat16*)(rec + (size_t)NBINS * CAP); // N*64
    __hip_bfloat16* h2s = h1u + (size_t)N * 64;                          // N*32

    hipMemsetAsync(cursor, 0, (1024 + NP) * sizeof(int), stream);
    fused_pass1_gemm1<<<P1B + GB, 256, 0, stream>>>(x, W1, h1u, src, dst,
                                                    cursor, cnt, rec);
    agg1_gemm2_ep<<<NBINS, 256, 0, stream>>>(h1u, rec, cursor, cnt, b1, W2,
                                             h2s);
    agg2_ep<<<NBINS, 256, 0, stream>>>(h2s, rec, cursor, cnt, b2, out);
}

// Round 8
// 309.766 us; speedup vs baseline: 3.8660x; 3.8660x over previous
//
#include <hip/hip_runtime.h>
#include <hip/hip_bf16.h>

// GCN 2-layer, N=100000, E=1.6M, 64->64(relu)->32.
// out[d] = dis[d]*(sum_{s in N(d)} dis[s]*h[s] + dis[d]*h[d]) + b  (per layer).
// Pipeline (3 kernels + memset), NO pedge materialization:
//  pass1+gemm1: partition edges into 1564 dst-range buckets (64 dsts each,
//    rec = (src<<6)|(dst&63)) + global per-dst degree cnt (1.6M atomics,
//    overlapped with 1563 gemm blocks) + x@W1 -> h1u bf16 (single rounding).
//  agg1_gemm2_fb: one block per bucket. Bins its rec bucket into LDS lists
//    (index-only binning, ~1k LDS-atomic increments), then r4's proven
//    per-node gather loops (8 lanes/node, 2 groups of 32 nodes) with
//    w = rsqrt(cnt[s]+1); z stays in LDS f32 (stride 68, bank-spread);
//    fused 64x32 gemm tile @ W2 -> h2s bf16 pre-scaled by dis[n].
//  agg2_fb: same self-binning, 4 lanes/node x 64 nodes, writes out f32.
// Established r3-r6: agg gather traffic is compulsory (each XCD pulls the
// whole table; ~95 MB at the ~2.3 TB/s random path) -- this round removes
// structure traffic (pass2 + pedge round trips), not the gather floor.
// r7 lesson: NO per-edge LDS f32 atomics (64 ds_add/edge = 710 us).

constexpr int N = 100000;
constexpr int E = 1600000;
constexpr int NBINS = 1564;    // dst-ranges of 64
constexpr int HB    = 1568;    // padded bin count for LDS scratch
constexpr int CAP   = 1536;    // records per range (mean 1023, +16 sigma)
constexpr int P1B   = 391;     // pass1 blocks (4096 edges each)
constexpr int GB    = 1563;    // gemm1 blocks (64 rows each)

// ---- fused: pass1 partition + degree count (bid<P1B) | gemm1 (else) ----
__global__ void __launch_bounds__(256) fused_pass1_gemm1(
    const float* __restrict__ x, const float* __restrict__ W1,
    __hip_bfloat16* __restrict__ h1u,
    const int* __restrict__ src, const int* __restrict__ dst,
    int* __restrict__ cursor, int* __restrict__ cnt,
    unsigned* __restrict__ rec) {
    __shared__ float ws[64][64];    // 16 KB (pass1 reuses as int scratch)
    __shared__ float xsT[64][64];   // 16 KB
    const int bid = blockIdx.x;
    const int t = threadIdx.x;
    if (bid < P1B) {
        int* hist  = (int*)ws;          // HB
        int* rbase = hist + HB;         // HB
        int* rcur  = rbase + HB;        // HB  (3*1568*4 = 18.8 KB < 32 KB)
        for (int i = t; i < HB; i += 256) hist[i] = 0;
        __syncthreads();
        int myd[16], mys[16];
        const int e0 = bid * 4096;
#pragma unroll
        for (int it = 0; it < 16; ++it) {
            int idx = e0 + it * 256 + t;
            bool ok = idx < E;
            myd[it] = ok ? dst[idx] : -1;
            mys[it] = ok ? src[idx] : 0;
            if (ok) {
                atomicAdd(&hist[myd[it] >> 6], 1);
                atomicAdd(&cnt[myd[it]], 1);   // global degree (no-return)
            }
        }
        __syncthreads();
        for (int i = t; i < HB; i += 256) {
            int h = hist[i];
            rbase[i] = (h > 0) ? atomicAdd(&cursor[i], h) : 0;
            rcur[i] = 0;
        }
        __syncthreads();
#pragma unroll
        for (int it = 0; it < 16; ++it) {
            if (myd[it] >= 0) {
                int cb = myd[it] >> 6;
                int r = atomicAdd(&rcur[cb], 1);
                int pos = rbase[cb] + r;
                if (pos < CAP)
                    rec[(size_t)cb * CAP + pos] =
                        ((unsigned)mys[it] << 6) | ((unsigned)myd[it] & 63u);
            }
        }
    } else {
        // ---- gemm block: 64 rows, outer-product 4x4 per thread ----
        const int row0 = (bid - P1B) * 64;
        for (int i = t * 4; i < 64 * 64; i += 1024) {
            float4 v = *(const float4*)(W1 + i);
            ws[i >> 6][i & 63]       = v.x;
            ws[i >> 6][(i & 63) + 1] = v.y;
            ws[i >> 6][(i & 63) + 2] = v.z;
            ws[i >> 6][(i & 63) + 3] = v.w;
        }
        {
            const int r  = t & 63;
            const int k0 = (t >> 6) * 16;
            const int gr = row0 + r;
            if (gr < N) {
#pragma unroll
                for (int kk = 0; kk < 16; kk += 4) {
                    float4 v = *(const float4*)(x + (size_t)gr * 64 + k0 + kk);
                    xsT[k0 + kk][r]     = v.x;
                    xsT[k0 + kk + 1][r] = v.y;
                    xsT[k0 + kk + 2][r] = v.z;
                    xsT[k0 + kk + 3][r] = v.w;
                }
            } else {
#pragma unroll
                for (int kk = 0; kk < 16; ++kk) xsT[k0 + kk][r] = 0.0f;
            }
        }
        __syncthreads();
        const int c4 = (t & 15) * 4;
        const int r4 = (t >> 4) * 4;
        float acc[4][4];
#pragma unroll
        for (int i = 0; i < 4; ++i)
#pragma unroll
            for (int j = 0; j < 4; ++j) acc[i][j] = 0.0f;
#pragma unroll 4
        for (int k = 0; k < 64; ++k) {
            float4 wv = *(const float4*)&ws[k][c4];
            float4 xv = *(const float4*)&xsT[k][r4];
            float xa[4] = {xv.x, xv.y, xv.z, xv.w};
            float wa[4] = {wv.x, wv.y, wv.z, wv.w};
#pragma unroll
            for (int i = 0; i < 4; ++i)
#pragma unroll
                for (int j = 0; j < 4; ++j) acc[i][j] += xa[i] * wa[j];
        }
#pragma unroll
        for (int i = 0; i < 4; ++i) {
            const int gr = row0 + r4 + i;
            if (gr < N) {
                unsigned short o[4];
#pragma unroll
                for (int j = 0; j < 4; ++j)
                    o[j] = __bfloat16_as_ushort(__float2bfloat16(acc[i][j]));
                *(ushort4*)((unsigned short*)h1u + (size_t)gr * 64 + c4) =
                    *(const ushort4*)o;
            }
        }
    }
}

__device__ __forceinline__ void bf8_fma(float* acc, uint4 r, float w) {
    const unsigned u[4] = {r.x, r.y, r.z, r.w};
#pragma unroll
    for (int k = 0; k < 4; ++k) {
        acc[2 * k]     += __uint_as_float(u[k] << 16) * w;
        acc[2 * k + 1] += __uint_as_float(u[k] & 0xffff0000u) * w;
    }
}

__device__ __forceinline__ void bf8_acc(float* acc, uint4 r) {
    const unsigned u[4] = {r.x, r.y, r.z, r.w};
#pragma unroll
    for (int k = 0; k < 4; ++k) {
        acc[2 * k]     += __uint_as_float(u[k] << 16);
        acc[2 * k + 1] += __uint_as_float(u[k] & 0xffff0000u);
    }
}

// ---- fused layer-1 agg + gemm2: one block per 64-dst bucket.
// Phase A: bin rec bucket -> LDS lists (index-only).
// Phase B: per-node weighted gathers (8 lanes/node, 2 groups of 32 nodes),
//          z = relu(dis*acc + b) into LDS f32 (stride 68).
// Phase C: 64x32 gemm tile @ W2 -> h2s bf16 pre-scaled by dis[n]. ----
__global__ void __launch_bounds__(256) agg1_gemm2_fb(
    const __hip_bfloat16* __restrict__ h1u, const unsigned* __restrict__ rec,
    const int* __restrict__ cursor, const int* __restrict__ cnt,
    const float* __restrict__ b, const float* __restrict__ W2,
    __hip_bfloat16* __restrict__ h2s) {
    __shared__ float    ws[64][32];      // 8 KB  W2
    __shared__ float    zs[64 * 68];     // 17.4 KB z rows, bank-spread
    __shared__ unsigned lists[64 * 64];  // 16 KB per-node src lists
    __shared__ int      cur[64];
    __shared__ float    dis_l[64];
    const int t = threadIdx.x;
    const int cb = blockIdx.x;
    for (int i = t; i < 64 * 32; i += 256) ws[i >> 5][i & 31] = W2[i];
    if (t < 64) cur[t] = 0;
    __syncthreads();

    // Phase A: bin
    int m = cursor[cb];
    if (m > CAP) m = CAP;
    const unsigned* rb_ = rec + (size_t)cb * CAP;
    for (int i = t; i < m; i += 256) {
        unsigned u = rb_[i];
        int dl = (int)(u & 63u);
        int r = atomicAdd(&cur[dl], 1);
        if (r < 64) lists[dl * 64 + r] = u >> 6;
    }
    __syncthreads();

    // Phase B: gather
    const unsigned short* hp = (const unsigned short*)h1u;
    const int row0 = cb * 64;
    const int oct = t & 7;
    const int fq = oct * 8;
    float4 b0v = *(const float4*)(b + fq);
    float4 b1v = *(const float4*)(b + fq + 4);
    float bb[8] = {b0v.x, b0v.y, b0v.z, b0v.w, b1v.x, b1v.y, b1v.z, b1v.w};
#pragma unroll
    for (int g = 0; g < 2; ++g) {
        const int nl = g * 32 + (t >> 3);
        const int n = row0 + nl;
        const int c = cur[nl];
        const int deg = (c < 64) ? c : 64;
        const unsigned* lp = &lists[nl * 64];
        float acc[8];
#pragma unroll
        for (int i = 0; i < 8; ++i) acc[i] = 0.0f;
        int j = 0;
        for (; j + 2 <= deg; j += 2) {
            unsigned s0 = lp[j], s1 = lp[j + 1];
            float w0 = rsqrtf((float)cnt[s0] + 1.0f);
            float w1 = rsqrtf((float)cnt[s1] + 1.0f);
            uint4 r0 = *(const uint4*)(hp + (size_t)s0 * 64 + fq);
            uint4 r1 = *(const uint4*)(hp + (size_t)s1 * 64 + fq);
            bf8_fma(acc, r0, w0);
            bf8_fma(acc, r1, w1);
        }
        if (j < deg) {
            unsigned s0 = lp[j];
            float w0 = rsqrtf((float)cnt[s0] + 1.0f);
            uint4 r0 = *(const uint4*)(hp + (size_t)s0 * 64 + fq);
            bf8_fma(acc, r0, w0);
        }
        if (n < N) {
            const float dn = rsqrtf((float)cnt[n] + 1.0f);
            uint4 sr = *(const uint4*)(hp + (size_t)n * 64 + fq);
            bf8_fma(acc, sr, dn);  // self term
            if (oct == 0) dis_l[nl] = dn;
            float* zr = &zs[nl * 68 + fq];
            float o[8];
#pragma unroll
            for (int i = 0; i < 8; ++i) o[i] = fmaxf(dn * acc[i] + bb[i], 0.0f);
            *(float4*)(zr)     = make_float4(o[0], o[1], o[2], o[3]);
            *(float4*)(zr + 4) = make_float4(o[4], o[5], o[6], o[7]);
        }
    }
    __syncthreads();

    // Phase C: gemm 64x32, thread = 1 col x 4 rows x 2 groups
    const int cc = t & 31;
    const int rbse = (t >> 5) * 4;
#pragma unroll
    for (int g = 0; g < 2; ++g) {
        const int r0_ = g * 32 + rbse;
        float oacc[4] = {0.f, 0.f, 0.f, 0.f};
        for (int k0 = 0; k0 < 64; k0 += 4) {
            float w0 = ws[k0][cc], w1 = ws[k0 + 1][cc];
            float w2 = ws[k0 + 2][cc], w3 = ws[k0 + 3][cc];
#pragma unroll
            for (int ii = 0; ii < 4; ++ii) {
                float4 xv = *(const float4*)&zs[(r0_ + ii) * 68 + k0];
                oacc[ii] += xv.x * w0 + xv.y * w1 + xv.z * w2 + xv.w * w3;
            }
        }
#pragma unroll
        for (int ii = 0; ii < 4; ++ii) {
            const int row = row0 + r0_ + ii;
            if (row < N)
                ((unsigned short*)h2s)[(size_t)row * 32 + cc] =
                    __bfloat16_as_ushort(
                        __float2bfloat16(oacc[ii] * dis_l[r0_ + ii]));
        }
    }
}

// ---- layer-2 agg: one block per bucket, self-binned; 4 lanes/node x 64.
// h2s pre-scaled by dis; pure accumulation. ----
__global__ void __launch_bounds__(256) agg2_fb(
    const __hip_bfloat16* __restrict__ h2s, const unsigned* __restrict__ rec,
    const int* __restrict__ cursor, const int* __restrict__ cnt,
    const float* __restrict__ b, float* __restrict__ out) {
    __shared__ unsigned lists[64 * 64];  // 16 KB
    __shared__ int cur[64];
    const int t = threadIdx.x;
    const int cb = blockIdx.x;
    if (t < 64) cur[t] = 0;
    __syncthreads();
    int m = cursor[cb];
    if (m > CAP) m = CAP;
    const unsigned* rb_ = rec + (size_t)cb * CAP;
    for (int i = t; i < m; i += 256) {
        unsigned u = rb_[i];
        int dl = (int)(u & 63u);
        int r = atomicAdd(&cur[dl], 1);
        if (r < 64) lists[dl * 64 + r] = u >> 6;
    }
    __syncthreads();

    const unsigned short* hp = (const unsigned short*)h2s;
    const int row0 = cb * 64;
    const int nl = t >> 2;
    const int n = row0 + nl;
    const int fq = (t & 3) * 8;
    const int c = cur[nl];
    const int deg = (c < 64) ? c : 64;
    const unsigned* lp = &lists[nl * 64];
    float acc[8];
#pragma unroll
    for (int i = 0; i < 8; ++i) acc[i] = 0.0f;
    int j = 0;
    for (; j + 2 <= deg; j += 2) {
        unsigned s0 = lp[j], s1 = lp[j + 1];
        uint4 r0 = *(const uint4*)(hp + (size_t)s0 * 32 + fq);
        uint4 r1 = *(const uint4*)(hp + (size_t)s1 * 32 + fq);
        bf8_acc(acc, r0);
        bf8_acc(acc, r1);
    }
    if (j < deg) {
        unsigned s0 = lp[j];
        uint4 r0 = *(const uint4*)(hp + (size_t)s0 * 32 + fq);
        bf8_acc(acc, r0);
    }
    if (n >= N) return;
    uint4 sr = *(const uint4*)(hp + (size_t)n * 32 + fq);
    bf8_acc(acc, sr);  // self term (h2s already has one dis factor)
    const float dn = rsqrtf((float)cnt[n] + 1.0f);
    float4 b0 = *(const float4*)(b + fq);
    float4 b1 = *(const float4*)(b + fq + 4);
    *(float4*)(out + (size_t)n * 32 + fq) =
        make_float4(dn * acc[0] + b0.x, dn * acc[1] + b0.y,
                    dn * acc[2] + b0.z, dn * acc[3] + b0.w);
    *(float4*)(out + (size_t)n * 32 + fq + 4) =
        make_float4(dn * acc[4] + b1.x, dn * acc[5] + b1.y,
                    dn * acc[6] + b1.z, dn * acc[7] + b1.w);
}

extern "C" void kernel_launch(void* const* d_in, const int* in_sizes, int n_in,
                              void* d_out, int out_size, void* d_ws, size_t ws_size,
                              hipStream_t stream) {
    const float* x  = (const float*)d_in[0];
    const int*   ei = (const int*)d_in[1];
    const float* W1 = (const float*)d_in[2];
    const float* b1 = (const float*)d_in[3];
    const float* W2 = (const float*)d_in[4];
    const float* b2 = (const float*)d_in[5];
    float* out = (float*)d_out;

    const int* src = ei;
    const int* dst = ei + E;

    constexpr size_t NP = 100352;
    int*      cursor = (int*)d_ws;                             // 2048 ints
    int*      cnt    = cursor + 2048;                          // NP ints
    unsigned* rec    = (unsigned*)(cnt + NP);                  // NBINS*CAP u32 (9.6 MB)
    __hip_bfloat16* h1u = (__hip_bfloat16*)(rec + (size_t)NBINS * CAP); // N*64
    __hip_bfloat16* h2s = h1u + (size_t)N * 64;                          // N*32

    hipMemsetAsync(cursor, 0, (2048 + NP) * sizeof(int), stream);
    fused_pass1_gemm1<<<P1B + GB, 256, 0, stream>>>(x, W1, h1u, src, dst,
                                                    cursor, cnt, rec);
    agg1_gemm2_fb<<<NBINS, 256, 0, stream>>>(h1u, rec, cursor, cnt, b1, W2,
                                             h2s);
    agg2_fb<<<NBINS, 256, 0, stream>>>(h2s, rec, cursor, cnt, b2, out);
}

// Round 9
// 227.367 us; speedup vs baseline: 5.2671x; 1.3624x over previous
//
#include <hip/hip_runtime.h>
#include <hip/hip_bf16.h>

// GCN 2-layer, N=100000, E=1.6M, 64->64(relu)->32.
// out[d] = dis[d]*(sum_{s in N(d)} dis[s]*h[s] + dis[d]*h[d]) + b  (per layer).
// Pipeline (4 kernels + memset), NO pedge materialization:
//  pass1+gemm1: partition edges into 1563 dst-range buckets (64 dsts each,
//    rec = (src<<6)|(dst&63)) + global per-dst degree cnt (1.6M atomics,
//    overlapped with 1563 gemm blocks) + x@W1 -> h1u bf16 (single rounding).
//  agg1_fb: one block (512 thr) per bucket. Bins its rec bucket into LDS
//    lists (index-only, 16.2 KB LDS -> ~4 blocks/CU), then per-node weighted
//    gathers (8 lanes/node, w = rsqrt(cnt[s]+1)); z1 bf16 out (r0 rounding).
//  gemm2: 32-row tile, z1 @ W2 -> h2s bf16 pre-scaled by dis[n].
//  agg2_fb: same self-binning (256 thr), 4 lanes/node x 64, writes out f32.
// r8 lessons: self-binning is fine (agg2_fb under radar; FETCH dropped to
// 84 MB) but 42.5 KB LDS collapsed occupancy to 10% -> NEVER fuse the gemm
// (25 KB extra LDS) into the gather block. r7: no per-edge LDS f32 atomics.
// r3-r6: gather FETCH ~85-97 MB is compulsory (each XCD pulls the table).

constexpr int N = 100000;
constexpr int E = 1600000;
constexpr int NBINS = 1563;    // ceil(N/64) dst-ranges of 64
constexpr int HB    = 1568;    // padded bin count for pass1 LDS scratch
constexpr int CAP   = 1536;    // records per range (mean 1023, +16 sigma)
constexpr int P1B   = 391;     // pass1 blocks (4096 edges each)
constexpr int GB    = 1563;    // gemm1 blocks (64 rows each)

// ---- fused: pass1 partition + degree count (bid<P1B) | gemm1 (else) ----
__global__ void __launch_bounds__(256) fused_pass1_gemm1(
    const float* __restrict__ x, const float* __restrict__ W1,
    __hip_bfloat16* __restrict__ h1u,
    const int* __restrict__ src, const int* __restrict__ dst,
    int* __restrict__ cursor, int* __restrict__ cnt,
    unsigned* __restrict__ rec) {
    __shared__ float ws[64][64];    // 16 KB (pass1 reuses ws+xsT as scratch)
    __shared__ float xsT[64][64];   // 16 KB
    const int bid = blockIdx.x;
    const int t = threadIdx.x;
    if (bid < P1B) {
        int* hist  = (int*)ws;          // HB ints (overflows into xsT: ok,
        int* rbase = hist + HB;         // both arrays unused by pass1 blocks)
        int* rcur  = rbase + HB;
        for (int i = t; i < HB; i += 256) hist[i] = 0;
        __syncthreads();
        int myd[16], mys[16];
        const int e0 = bid * 4096;
#pragma unroll
        for (int it = 0; it < 16; ++it) {
            int idx = e0 + it * 256 + t;
            bool ok = idx < E;
            myd[it] = ok ? dst[idx] : -1;
            mys[it] = ok ? src[idx] : 0;
            if (ok) {
                atomicAdd(&hist[myd[it] >> 6], 1);
                atomicAdd(&cnt[myd[it]], 1);   // global degree (no-return)
            }
        }
        __syncthreads();
        for (int i = t; i < HB; i += 256) {
            int h = hist[i];
            rbase[i] = (h > 0) ? atomicAdd(&cursor[i], h) : 0;
            rcur[i] = 0;
        }
        __syncthreads();
#pragma unroll
        for (int it = 0; it < 16; ++it) {
            if (myd[it] >= 0) {
                int cb = myd[it] >> 6;
                int r = atomicAdd(&rcur[cb], 1);
                int pos = rbase[cb] + r;
                if (pos < CAP)
                    rec[(size_t)cb * CAP + pos] =
                        ((unsigned)mys[it] << 6) | ((unsigned)myd[it] & 63u);
            }
        }
    } else {
        // ---- gemm block: 64 rows, outer-product 4x4 per thread ----
        const int row0 = (bid - P1B) * 64;
        for (int i = t * 4; i < 64 * 64; i += 1024) {
            float4 v = *(const float4*)(W1 + i);
            ws[i >> 6][i & 63]       = v.x;
            ws[i >> 6][(i & 63) + 1] = v.y;
            ws[i >> 6][(i & 63) + 2] = v.z;
            ws[i >> 6][(i & 63) + 3] = v.w;
        }
        {
            const int r  = t & 63;
            const int k0 = (t >> 6) * 16;
            const int gr = row0 + r;
            if (gr < N) {
#pragma unroll
                for (int kk = 0; kk < 16; kk += 4) {
                    float4 v = *(const float4*)(x + (size_t)gr * 64 + k0 + kk);
                    xsT[k0 + kk][r]     = v.x;
                    xsT[k0 + kk + 1][r] = v.y;
                    xsT[k0 + kk + 2][r] = v.z;
                    xsT[k0 + kk + 3][r] = v.w;
                }
            } else {
#pragma unroll
                for (int kk = 0; kk < 16; ++kk) xsT[k0 + kk][r] = 0.0f;
            }
        }
        __syncthreads();
        const int c4 = (t & 15) * 4;
        const int r4 = (t >> 4) * 4;
        float acc[4][4];
#pragma unroll
        for (int i = 0; i < 4; ++i)
#pragma unroll
            for (int j = 0; j < 4; ++j) acc[i][j] = 0.0f;
#pragma unroll 4
        for (int k = 0; k < 64; ++k) {
            float4 wv = *(const float4*)&ws[k][c4];
            float4 xv = *(const float4*)&xsT[k][r4];
            float xa[4] = {xv.x, xv.y, xv.z, xv.w};
            float wa[4] = {wv.x, wv.y, wv.z, wv.w};
#pragma unroll
            for (int i = 0; i < 4; ++i)
#pragma unroll
                for (int j = 0; j < 4; ++j) acc[i][j] += xa[i] * wa[j];
        }
#pragma unroll
        for (int i = 0; i < 4; ++i) {
            const int gr = row0 + r4 + i;
            if (gr < N) {
                unsigned short o[4];
#pragma unroll
                for (int j = 0; j < 4; ++j)
                    o[j] = __bfloat16_as_ushort(__float2bfloat16(acc[i][j]));
                *(ushort4*)((unsigned short*)h1u + (size_t)gr * 64 + c4) =
                    *(const ushort4*)o;
            }
        }
    }
}

__device__ __forceinline__ void bf8_fma(float* acc, uint4 r, float w) {
    const unsigned u[4] = {r.x, r.y, r.z, r.w};
#pragma unroll
    for (int k = 0; k < 4; ++k) {
        acc[2 * k]     += __uint_as_float(u[k] << 16) * w;
        acc[2 * k + 1] += __uint_as_float(u[k] & 0xffff0000u) * w;
    }
}

__device__ __forceinline__ void bf8_acc(float* acc, uint4 r) {
    const unsigned u[4] = {r.x, r.y, r.z, r.w};
#pragma unroll
    for (int k = 0; k < 4; ++k) {
        acc[2 * k]     += __uint_as_float(u[k] << 16);
        acc[2 * k + 1] += __uint_as_float(u[k] & 0xffff0000u);
    }
}

// ---- layer-1 agg, self-binned: one 512-thr block per 64-dst bucket.
// Phase A: bin rec bucket -> LDS lists (index-only, 16.2 KB total LDS).
// Phase B: 8 lanes/node weighted gathers, w = rsqrt(cnt[s]+1);
//          z1 = relu(dis[n]*(acc + dis[n]*h1[n]) + b) -> bf16 (r0 chain). ----
__global__ void __launch_bounds__(512) agg1_fb(
    const __hip_bfloat16* __restrict__ h1u, const unsigned* __restrict__ rec,
    const int* __restrict__ cursor, const int* __restrict__ cnt,
    const float* __restrict__ b, __hip_bfloat16* __restrict__ z1) {
    __shared__ unsigned lists[64 * 64];  // 16 KB
    __shared__ int cur[64];
    const int t = threadIdx.x;
    const int cb = blockIdx.x;
    if (t < 64) cur[t] = 0;
    __syncthreads();
    int m = cursor[cb];
    if (m > CAP) m = CAP;
    const unsigned* rb_ = rec + (size_t)cb * CAP;
    for (int i = t; i < m; i += 512) {
        unsigned u = rb_[i];
        int dl = (int)(u & 63u);
        int r = atomicAdd(&cur[dl], 1);
        if (r < 64) lists[dl * 64 + r] = u >> 6;
    }
    __syncthreads();

    const unsigned short* hp = (const unsigned short*)h1u;
    const int row0 = cb * 64;
    const int nl = t >> 3;
    const int n = row0 + nl;
    const int fq = (t & 7) * 8;
    const int c = cur[nl];
    const int deg = (c < 64) ? c : 64;
    const unsigned* lp = &lists[nl * 64];
    float acc[8];
#pragma unroll
    for (int i = 0; i < 8; ++i) acc[i] = 0.0f;
    int j = 0;
    for (; j + 2 <= deg; j += 2) {
        unsigned s0 = lp[j], s1 = lp[j + 1];
        float w0 = rsqrtf((float)cnt[s0] + 1.0f);
        float w1 = rsqrtf((float)cnt[s1] + 1.0f);
        uint4 r0 = *(const uint4*)(hp + (size_t)s0 * 64 + fq);
        uint4 r1 = *(const uint4*)(hp + (size_t)s1 * 64 + fq);
        bf8_fma(acc, r0, w0);
        bf8_fma(acc, r1, w1);
    }
    if (j < deg) {
        unsigned s0 = lp[j];
        float w0 = rsqrtf((float)cnt[s0] + 1.0f);
        uint4 r0 = *(const uint4*)(hp + (size_t)s0 * 64 + fq);
        bf8_fma(acc, r0, w0);
    }
    if (n >= N) return;
    const float dn = rsqrtf((float)cnt[n] + 1.0f);
    uint4 sr = *(const uint4*)(hp + (size_t)n * 64 + fq);
    bf8_fma(acc, sr, dn);  // self term: dis[n]*h1[n]
    float4 b0v = *(const float4*)(b + fq);
    float4 b1v = *(const float4*)(b + fq + 4);
    float bb[8] = {b0v.x, b0v.y, b0v.z, b0v.w, b1v.x, b1v.y, b1v.z, b1v.w};
    unsigned short o[8];
#pragma unroll
    for (int i = 0; i < 8; ++i) {
        float v = fmaxf(dn * acc[i] + bb[i], 0.0f);
        o[i] = __bfloat16_as_ushort(__float2bfloat16(v));
    }
    *(uint4*)((unsigned short*)z1 + (size_t)n * 64 + fq) = *(const uint4*)o;
}

// ---- gemm2: h2s[n] = (z1 @ W2)[n] * dis[n] -> bf16 (r0-proven) ----
__global__ void __launch_bounds__(256) gemm2_kernel(
    const __hip_bfloat16* __restrict__ Z, const float* __restrict__ W2,
    const int* __restrict__ cnt, __hip_bfloat16* __restrict__ H2) {
    __shared__ float ws[64][32];
    __shared__ float xs[32][64];
    const int t = threadIdx.x;
    for (int i = t; i < 64 * 32; i += 256) ws[i >> 5][i & 31] = W2[i];
    const int row0 = blockIdx.x * 32;
    const unsigned short* Zp = (const unsigned short*)Z;
#pragma unroll
    for (int h = 0; h < 2; ++h) {
        int idx = h * 1024 + t * 4;
        int r = idx >> 6, k = idx & 63;
        ushort4 v = *(const ushort4*)(Zp + (size_t)(row0 + r) * 64 + k);
        xs[r][k]     = __uint_as_float((unsigned)v.x << 16);
        xs[r][k + 1] = __uint_as_float((unsigned)v.y << 16);
        xs[r][k + 2] = __uint_as_float((unsigned)v.z << 16);
        xs[r][k + 3] = __uint_as_float((unsigned)v.w << 16);
    }
    __syncthreads();
    const int c  = t & 31;
    const int rb = (t >> 5) * 4;
    float acc[4] = {0.f, 0.f, 0.f, 0.f};
    for (int k0 = 0; k0 < 64; k0 += 4) {
        float w0 = ws[k0][c], w1 = ws[k0 + 1][c];
        float w2 = ws[k0 + 2][c], w3 = ws[k0 + 3][c];
#pragma unroll
        for (int i = 0; i < 4; ++i) {
            float4 xv = *(const float4*)&xs[rb + i][k0];
            acc[i] += xv.x * w0;
            acc[i] += xv.y * w1;
            acc[i] += xv.z * w2;
            acc[i] += xv.w * w3;
        }
    }
#pragma unroll
    for (int i = 0; i < 4; ++i) {
        int row = row0 + rb + i;
        float dn = rsqrtf((float)cnt[row] + 1.0f);
        H2[(size_t)row * 32 + c] = __float2bfloat16(acc[i] * dn);
    }
}

// ---- layer-2 agg: self-binned, 256 thr, 4 lanes/node x 64 (r8-proven).
// h2s pre-scaled by dis; pure accumulation. ----
__global__ void __launch_bounds__(256) agg2_fb(
    const __hip_bfloat16* __restrict__ h2s, const unsigned* __restrict__ rec,
    const int* __restrict__ cursor, const int* __restrict__ cnt,
    const float* __restrict__ b, float* __restrict__ out) {
    __shared__ unsigned lists[64 * 64];  // 16 KB
    __shared__ int cur[64];
    const int t = threadIdx.x;
    const int cb = blockIdx.x;
    if (t < 64) cur[t] = 0;
    __syncthreads();
    int m = cursor[cb];
    if (m > CAP) m = CAP;
    const unsigned* rb_ = rec + (size_t)cb * CAP;
    for (int i = t; i < m; i += 256) {
        unsigned u = rb_[i];
        int dl = (int)(u & 63u);
        int r = atomicAdd(&cur[dl], 1);
        if (r < 64) lists[dl * 64 + r] = u >> 6;
    }
    __syncthreads();

    const unsigned short* hp = (const unsigned short*)h2s;
    const int row0 = cb * 64;
    const int nl = t >> 2;
    const int n = row0 + nl;
    const int fq = (t & 3) * 8;
    const int c = cur[nl];
    const int deg = (c < 64) ? c : 64;
    const unsigned* lp = &lists[nl * 64];
    float acc[8];
#pragma unroll
    for (int i = 0; i < 8; ++i) acc[i] = 0.0f;
    int j = 0;
    for (; j + 2 <= deg; j += 2) {
        unsigned s0 = lp[j], s1 = lp[j + 1];
        uint4 r0 = *(const uint4*)(hp + (size_t)s0 * 32 + fq);
        uint4 r1 = *(const uint4*)(hp + (size_t)s1 * 32 + fq);
        bf8_acc(acc, r0);
        bf8_acc(acc, r1);
    }
    if (j < deg) {
        unsigned s0 = lp[j];
        uint4 r0 = *(const uint4*)(hp + (size_t)s0 * 32 + fq);
        bf8_acc(acc, r0);
    }
    if (n >= N) return;
    uint4 sr = *(const uint4*)(hp + (size_t)n * 32 + fq);
    bf8_acc(acc, sr);  // self term (h2s already has one dis factor)
    const float dn = rsqrtf((float)cnt[n] + 1.0f);
    float4 b0 = *(const float4*)(b + fq);
    float4 b1 = *(const float4*)(b + fq + 4);
    *(float4*)(out + (size_t)n * 32 + fq) =
        make_float4(dn * acc[0] + b0.x, dn * acc[1] + b0.y,
                    dn * acc[2] + b0.z, dn * acc[3] + b0.w);
    *(float4*)(out + (size_t)n * 32 + fq + 4) =
        make_float4(dn * acc[4] + b1.x, dn * acc[5] + b1.y,
                    dn * acc[6] + b1.z, dn * acc[7] + b1.w);
}

extern "C" void kernel_launch(void* const* d_in, const int* in_sizes, int n_in,
                              void* d_out, int out_size, void* d_ws, size_t ws_size,
                              hipStream_t stream) {
    const float* x  = (const float*)d_in[0];
    const int*   ei = (const int*)d_in[1];
    const float* W1 = (const float*)d_in[2];
    const float* b1 = (const float*)d_in[3];
    const float* W2 = (const float*)d_in[4];
    const float* b2 = (const float*)d_in[5];
    float* out = (float*)d_out;

    const int* src = ei;
    const int* dst = ei + E;

    constexpr size_t NP = 100352;
    int*      cursor = (int*)d_ws;                             // 2048 ints
    int*      cnt    = cursor + 2048;                          // NP ints
    unsigned* rec    = (unsigned*)(cnt + NP);                  // NBINS*CAP u32 (9.6 MB)
    __hip_bfloat16* h1u = (__hip_bfloat16*)(rec + (size_t)NBINS * CAP); // N*64
    __hip_bfloat16* z1b = h1u + (size_t)N * 64;                          // N*64
    __hip_bfloat16* h2s = z1b + (size_t)N * 64;                          // N*32

    hipMemsetAsync(cursor, 0, (2048 + NP) * sizeof(int), stream);
    fused_pass1_gemm1<<<P1B + GB, 256, 0, stream>>>(x, W1, h1u, src, dst,
                                                    cursor, cnt, rec);
    agg1_fb<<<NBINS, 512, 0, stream>>>(h1u, rec, cursor, cnt, b1, z1b);
    gemm2_kernel<<<N / 32, 256, 0, stream>>>(z1b, W2, cnt, h2s);
    agg2_fb<<<NBINS, 256, 0, stream>>>(h2s, rec, cursor, cnt, b2, out);
}

// Round 11
// 185.134 us; speedup vs baseline: 6.4686x; 1.2281x over previous
//
#include <hip/hip_runtime.h>
#include <hip/hip_bf16.h>

// GCN 2-layer, N=100000, E=1.6M, 64->64(relu)->32.
// out[d] = dis[d]*(sum_{s in N(d)} dis[s]*h[s] + dis[d]*h[d]) + b  (per layer).
// Pipeline (5 kernels + memset), NO pedge, NO global degree atomics:
//  pass1+gemm1: partition edges into 1563 dst-range buckets (64 dsts each,
//    rec = (src<<6)|(dst&63)); x@W1 -> h1u bf16 (single rounding).
//    NO per-edge global atomics (r9: 1.6M cnt atomics = +60MB RMW, 2x dur).
//  degree_kernel: one block per bucket re-scans rec, LDS-histograms the
//    6-bit dst, writes dis[] = rsqrt(deg+1). Degrees come from binning.
//  agg1_fb: one 512-thr block per bucket. Bins rec into LDS lists (16.2 KB),
//    8 lanes/node weighted gathers (w = dis[s], L2-resident), dn from the
//    block's own cur[] -> z1 bf16 (r0 rounding chain).
//  gemm2: 32-row tile, z1 @ W2 -> h2s bf16 pre-scaled by dis[row].
//  agg2_fb: self-binned, 4 lanes/node x 64, dn local, writes out f32.
// Locked-in lessons: r7 no per-edge LDS f32 atomics; r8 no >32KB LDS in
// gather blocks (occupancy cliff); r9 no scattered global atomics; r3-r6
// gather FETCH ~85-97MB is compulsory (each XCD pulls the table) at ~2.3TB/s.

constexpr int N = 100000;
constexpr int E = 1600000;
constexpr int NBINS = 1563;    // ceil(N/64) dst-ranges of 64
constexpr int HB    = 1568;    // padded bin count for pass1 LDS scratch
constexpr int CAP   = 1536;    // records per range (mean 1023, +16 sigma)
constexpr int P1B   = 391;     // pass1 blocks (4096 edges each)
constexpr int GB    = 1563;    // gemm1 blocks (64 rows each)

// ---- fused: pass1 partition (bid<P1B) | gemm1 outer-product (else) ----
__global__ void __launch_bounds__(256) fused_pass1_gemm1(
    const float* __restrict__ x, const float* __restrict__ W1,
    __hip_bfloat16* __restrict__ h1u,
    const int* __restrict__ src, const int* __restrict__ dst,
    int* __restrict__ cursor, unsigned* __restrict__ rec) {
    __shared__ float ws[64][64];    // 16 KB (pass1 reuses ws+xsT as scratch)
    __shared__ float xsT[64][64];   // 16 KB
    const int bid = blockIdx.x;
    const int t = threadIdx.x;
    if (bid < P1B) {
        int* hist  = (int*)ws;          // HB ints (spills into xsT: both
        int* rbase = hist + HB;         // arrays unused by pass1 blocks)
        int* rcur  = rbase + HB;
        for (int i = t; i < HB; i += 256) hist[i] = 0;
        __syncthreads();
        int myd[16], mys[16];
        const int e0 = bid * 4096;
#pragma unroll
        for (int it = 0; it < 16; ++it) {
            int idx = e0 + it * 256 + t;
            bool ok = idx < E;
            myd[it] = ok ? dst[idx] : -1;
            mys[it] = ok ? src[idx] : 0;
            if (ok) atomicAdd(&hist[myd[it] >> 6], 1);
        }
        __syncthreads();
        for (int i = t; i < HB; i += 256) {
            int h = hist[i];
            rbase[i] = (h > 0) ? atomicAdd(&cursor[i], h) : 0;
            rcur[i] = 0;
        }
        __syncthreads();
#pragma unroll
        for (int it = 0; it < 16; ++it) {
            if (myd[it] >= 0) {
                int cb = myd[it] >> 6;
                int r = atomicAdd(&rcur[cb], 1);
                int pos = rbase[cb] + r;
                if (pos < CAP)
                    rec[(size_t)cb * CAP + pos] =
                        ((unsigned)mys[it] << 6) | ((unsigned)myd[it] & 63u);
            }
        }
    } else {
        // ---- gemm block: 64 rows, outer-product 4x4 per thread ----
        const int row0 = (bid - P1B) * 64;
        for (int i = t * 4; i < 64 * 64; i += 1024) {
            float4 v = *(const float4*)(W1 + i);
            ws[i >> 6][i & 63]       = v.x;
            ws[i >> 6][(i & 63) + 1] = v.y;
            ws[i >> 6][(i & 63) + 2] = v.z;
            ws[i >> 6][(i & 63) + 3] = v.w;
        }
        {
            const int r  = t & 63;
            const int k0 = (t >> 6) * 16;
            const int gr = row0 + r;
            if (gr < N) {
#pragma unroll
                for (int kk = 0; kk < 16; kk += 4) {
                    float4 v = *(const float4*)(x + (size_t)gr * 64 + k0 + kk);
                    xsT[k0 + kk][r]     = v.x;
                    xsT[k0 + kk + 1][r] = v.y;
                    xsT[k0 + kk + 2][r] = v.z;
                    xsT[k0 + kk + 3][r] = v.w;
                }
            } else {
#pragma unroll
                for (int kk = 0; kk < 16; ++kk) xsT[k0 + kk][r] = 0.0f;
            }
        }
        __syncthreads();
        const int c4 = (t & 15) * 4;
        const int r4 = (t >> 4) * 4;
        float acc[4][4];
#pragma unroll
        for (int i = 0; i < 4; ++i)
#pragma unroll
            for (int j = 0; j < 4; ++j) acc[i][j] = 0.0f;
#pragma unroll 4
        for (int k = 0; k < 64; ++k) {
            float4 wv = *(const float4*)&ws[k][c4];
            float4 xv = *(const float4*)&xsT[k][r4];
            float xa[4] = {xv.x, xv.y, xv.z, xv.w};
            float wa[4] = {wv.x, wv.y, wv.z, wv.w};
#pragma unroll
            for (int i = 0; i < 4; ++i)
#pragma unroll
                for (int j = 0; j < 4; ++j) acc[i][j] += xa[i] * wa[j];
        }
#pragma unroll
        for (int i = 0; i < 4; ++i) {
            const int gr = row0 + r4 + i;
            if (gr < N) {
                unsigned short o[4];
#pragma unroll
                for (int j = 0; j < 4; ++j)
                    o[j] = __bfloat16_as_ushort(__float2bfloat16(acc[i][j]));
                *(ushort4*)((unsigned short*)h1u + (size_t)gr * 64 + c4) =
                    *(const ushort4*)o;
            }
        }
    }
}

// ---- degree: one block per bucket; histogram 6-bit dst -> dis[] ----
__global__ void __launch_bounds__(256) degree_kernel(
    const unsigned* __restrict__ rec, const int* __restrict__ cursor,
    float* __restrict__ dis) {
    __shared__ int cur[64];
    const int t = threadIdx.x;
    const int cb = blockIdx.x;
    if (t < 64) cur[t] = 0;
    __syncthreads();
    int m = cursor[cb];
    if (m > CAP) m = CAP;
    const unsigned* rb_ = rec + (size_t)cb * CAP;
    for (int i = t; i < m; i += 256)
        atomicAdd(&cur[rb_[i] & 63u], 1);
    __syncthreads();
    if (t < 64) {
        const int n = cb * 64 + t;
        if (n < N) dis[n] = rsqrtf((float)cur[t] + 1.0f);
    }
}

__device__ __forceinline__ void bf8_fma(float* acc, uint4 r, float w) {
    const unsigned u[4] = {r.x, r.y, r.z, r.w};
#pragma unroll
    for (int k = 0; k < 4; ++k) {
        acc[2 * k]     += __uint_as_float(u[k] << 16) * w;
        acc[2 * k + 1] += __uint_as_float(u[k] & 0xffff0000u) * w;
    }
}

__device__ __forceinline__ void bf8_acc(float* acc, uint4 r) {
    const unsigned u[4] = {r.x, r.y, r.z, r.w};
#pragma unroll
    for (int k = 0; k < 4; ++k) {
        acc[2 * k]     += __uint_as_float(u[k] << 16);
        acc[2 * k + 1] += __uint_as_float(u[k] & 0xffff0000u);
    }
}

// ---- layer-1 agg, self-binned: one 512-thr block per 64-dst bucket.
// Phase A: bin rec bucket -> LDS lists (index-only, 16.2 KB total LDS).
// Phase B: 8 lanes/node weighted gathers (w = dis[s]); dn from local cur;
//          z1 = relu(dn*(acc + dn*h1[n]) + b) -> bf16 (r0 chain). ----
__global__ void __launch_bounds__(512) agg1_fb(
    const __hip_bfloat16* __restrict__ h1u, const unsigned* __restrict__ rec,
    const int* __restrict__ cursor, const float* __restrict__ dis,
    const float* __restrict__ b, __hip_bfloat16* __restrict__ z1) {
    __shared__ unsigned lists[64 * 64];  // 16 KB
    __shared__ int cur[64];
    const int t = threadIdx.x;
    const int cb = blockIdx.x;
    if (t < 64) cur[t] = 0;
    __syncthreads();
    int m = cursor[cb];
    if (m > CAP) m = CAP;
    const unsigned* rb_ = rec + (size_t)cb * CAP;
    for (int i = t; i < m; i += 512) {
        unsigned u = rb_[i];
        int dl = (int)(u & 63u);
        int r = atomicAdd(&cur[dl], 1);
        if (r < 64) lists[dl * 64 + r] = u >> 6;
    }
    __syncthreads();

    const unsigned short* hp = (const unsigned short*)h1u;
    const int row0 = cb * 64;
    const int nl = t >> 3;
    const int n = row0 + nl;
    const int fq = (t & 7) * 8;
    const int c = cur[nl];
    const int deg = (c < 64) ? c : 64;
    const unsigned* lp = &lists[nl * 64];
    float acc[8];
#pragma unroll
    for (int i = 0; i < 8; ++i) acc[i] = 0.0f;
    int j = 0;
    for (; j + 2 <= deg; j += 2) {
        unsigned s0 = lp[j], s1 = lp[j + 1];
        float w0 = dis[s0], w1 = dis[s1];
        uint4 r0 = *(const uint4*)(hp + (size_t)s0 * 64 + fq);
        uint4 r1 = *(const uint4*)(hp + (size_t)s1 * 64 + fq);
        bf8_fma(acc, r0, w0);
        bf8_fma(acc, r1, w1);
    }
    if (j < deg) {
        unsigned s0 = lp[j];
        float w0 = dis[s0];
        uint4 r0 = *(const uint4*)(hp + (size_t)s0 * 64 + fq);
        bf8_fma(acc, r0, w0);
    }
    if (n >= N) return;
    const float dn = rsqrtf((float)c + 1.0f);
    uint4 sr = *(const uint4*)(hp + (size_t)n * 64 + fq);
    bf8_fma(acc, sr, dn);  // self term: dis[n]*h1[n]
    float4 b0v = *(const float4*)(b + fq);
    float4 b1v = *(const float4*)(b + fq + 4);
    float bb[8] = {b0v.x, b0v.y, b0v.z, b0v.w, b1v.x, b1v.y, b1v.z, b1v.w};
    unsigned short o[8];
#pragma unroll
    for (int i = 0; i < 8; ++i) {
        float v = fmaxf(dn * acc[i] + bb[i], 0.0f);
        o[i] = __bfloat16_as_ushort(__float2bfloat16(v));
    }
    *(uint4*)((unsigned short*)z1 + (size_t)n * 64 + fq) = *(const uint4*)o;
}

// ---- gemm2: h2s[n] = (z1 @ W2)[n] * dis[n] -> bf16 (r0-proven) ----
__global__ void __launch_bounds__(256) gemm2_kernel(
    const __hip_bfloat16* __restrict__ Z, const float* __restrict__ W2,
    const float* __restrict__ dis, __hip_bfloat16* __restrict__ H2) {
    __shared__ float ws[64][32];
    __shared__ float xs[32][64];
    const int t = threadIdx.x;
    for (int i = t; i < 64 * 32; i += 256) ws[i >> 5][i & 31] = W2[i];
    const int row0 = blockIdx.x * 32;
    const unsigned short* Zp = (const unsigned short*)Z;
#pragma unroll
    for (int h = 0; h < 2; ++h) {
        int idx = h * 1024 + t * 4;
        int r = idx >> 6, k = idx & 63;
        ushort4 v = *(const ushort4*)(Zp + (size_t)(row0 + r) * 64 + k);
        xs[r][k]     = __uint_as_float((unsigned)v.x << 16);
        xs[r][k + 1] = __uint_as_float((unsigned)v.y << 16);
        xs[r][k + 2] = __uint_as_float((unsigned)v.z << 16);
        xs[r][k + 3] = __uint_as_float((unsigned)v.w << 16);
    }
    __syncthreads();
    const int c  = t & 31;
    const int rb = (t >> 5) * 4;
    float acc[4] = {0.f, 0.f, 0.f, 0.f};
    for (int k0 = 0; k0 < 64; k0 += 4) {
        float w0 = ws[k0][c], w1 = ws[k0 + 1][c];
        float w2 = ws[k0 + 2][c], w3 = ws[k0 + 3][c];
#pragma unroll
        for (int i = 0; i < 4; ++i) {
            float4 xv = *(const float4*)&xs[rb + i][k0];
            acc[i] += xv.x * w0;
            acc[i] += xv.y * w1;
            acc[i] += xv.z * w2;
            acc[i] += xv.w * w3;
        }
    }
#pragma unroll
    for (int i = 0; i < 4; ++i) {
        int row = row0 + rb + i;
        H2[(size_t)row * 32 + c] = __float2bfloat16(acc[i] * dis[row]);
    }
}

// ---- layer-2 agg: self-binned, 256 thr, 4 lanes/node x 64.
// h2s pre-scaled by dis; pure accumulation; dn from local cur. ----
__global__ void __launch_bounds__(256) agg2_fb(
    const __hip_bfloat16* __restrict__ h2s, const unsigned* __restrict__ rec,
    const int* __restrict__ cursor, const float* __restrict__ b,
    float* __restrict__ out) {
    __shared__ unsigned lists[64 * 64];  // 16 KB
    __shared__ int cur[64];
    const int t = threadIdx.x;
    const int cb = blockIdx.x;
    if (t < 64) cur[t] = 0;
    __syncthreads();
    int m = cursor[cb];
    if (m > CAP) m = CAP;
    const unsigned* rb_ = rec + (size_t)cb * CAP;
    for (int i = t; i < m; i += 256) {
        unsigned u = rb_[i];
        int dl = (int)(u & 63u);
        int r = atomicAdd(&cur[dl], 1);
        if (r < 64) lists[dl * 64 + r] = u >> 6;
    }
    __syncthreads();

    const unsigned short* hp = (const unsigned short*)h2s;
    const int row0 = cb * 64;
    const int nl = t >> 2;
    const int n = row0 + nl;
    const int fq = (t & 3) * 8;
    const int c = cur[nl];
    const int deg = (c < 64) ? c : 64;
    const unsigned* lp = &lists[nl * 64];
    float acc[8];
#pragma unroll
    for (int i = 0; i < 8; ++i) acc[i] = 0.0f;
    int j = 0;
    for (; j + 2 <= deg; j += 2) {
        unsigned s0 = lp[j], s1 = lp[j + 1];
        uint4 r0 = *(const uint4*)(hp + (size_t)s0 * 32 + fq);
        uint4 r1 = *(const uint4*)(hp + (size_t)s1 * 32 + fq);
        bf8_acc(acc, r0);
        bf8_acc(acc, r1);
    }
    if (j < deg) {
        unsigned s0 = lp[j];
        uint4 r0 = *(const uint4*)(hp + (size_t)s0 * 32 + fq);
        bf8_acc(acc, r0);
    }
    if (n >= N) return;
    uint4 sr = *(const uint4*)(hp + (size_t)n * 32 + fq);
    bf8_acc(acc, sr);  // self term (h2s already has one dis factor)
    const float dn = rsqrtf((float)c + 1.0f);
    float4 b0 = *(const float4*)(b + fq);
    float4 b1 = *(const float4*)(b + fq + 4);
    *(float4*)(out + (size_t)n * 32 + fq) =
        make_float4(dn * acc[0] + b0.x, dn * acc[1] + b0.y,
                    dn * acc[2] + b0.z, dn * acc[3] + b0.w);
    *(float4*)(out + (size_t)n * 32 + fq + 4) =
        make_float4(dn * acc[4] + b1.x, dn * acc[5] + b1.y,
                    dn * acc[6] + b1.z, dn * acc[7] + b1.w);
}

extern "C" void kernel_launch(void* const* d_in, const int* in_sizes, int n_in,
                              void* d_out, int out_size, void* d_ws, size_t ws_size,
                              hipStream_t stream) {
    const float* x  = (const float*)d_in[0];
    const int*   ei = (const int*)d_in[1];
    const float* W1 = (const float*)d_in[2];
    const float* b1 = (const float*)d_in[3];
    const float* W2 = (const float*)d_in[4];
    const float* b2 = (const float*)d_in[5];
    float* out = (float*)d_out;

    const int* src = ei;
    const int* dst = ei + E;

    constexpr size_t NP = 100352;
    int*      cursor = (int*)d_ws;                             // 2048 ints
    float*    dis    = (float*)(cursor + 2048);                // NP floats
    unsigned* rec    = (unsigned*)(dis + NP);                  // NBINS*CAP u32 (9.6 MB)
    __hip_bfloat16* h1u = (__hip_bfloat16*)(rec + (size_t)NBINS * CAP); // N*64
    __hip_bfloat16* z1b = h1u + (size_t)N * 64;                          // N*64
    __hip_bfloat16* h2s = z1b + (size_t)N * 64;                          // N*32

    hipMemsetAsync(cursor, 0, 2048 * sizeof(int), stream);
    fused_pass1_gemm1<<<P1B + GB, 256, 0, stream>>>(x, W1, h1u, src, dst,
                                                    cursor, rec);
    degree_kernel<<<NBINS, 256, 0, stream>>>(rec, cursor, dis);
    agg1_fb<<<NBINS, 512, 0, stream>>>(h1u, rec, cursor, dis, b1, z1b);
    gemm2_kernel<<<N / 32, 256, 0, stream>>>(z1b, W2, dis, h2s);
    agg2_fb<<<NBINS, 256, 0, stream>>>(h2s, rec, cursor, b2, out);
}